// Round 1
// baseline (254.830 us; speedup 1.0000x reference)
//
#include <hip/hip_runtime.h>

// Problem constants (B,T,C,H fixed by the reference).
constexpr int Bn = 4, Tn = 2048, Cn = 1024, Hn = 16, Dn = 64;

typedef __attribute__((ext_vector_type(8))) short short8;
typedef __attribute__((ext_vector_type(4))) float floatx4;
typedef __attribute__((ext_vector_type(2))) unsigned uint2v;

#define DEVFN __device__ __forceinline__

// exp(s/8) = exp2(s * log2e/8); folded into Q at GEMM1 epilogue.
constexpr float SCL = 0.18033688011112042f;

// RTNE float -> bf16 raw bits (inputs are finite; no NaN handling needed).
DEVFN unsigned f2bf_u(float f) {
  unsigned u = __builtin_bit_cast(unsigned, f);
  u += 0x7fffu + ((u >> 16) & 1u);
  return u >> 16;
}
DEVFN short f2bf(float f) { return (short)f2bf_u(f); }

DEVFN floatx4 mfma16(short8 a, short8 b, floatx4 c) {
  return __builtin_amdgcn_mfma_f32_16x16x32_bf16(a, b, c, 0, 0, 0);
}

// Async global->LDS, 16B/lane. LDS dest must be wave-uniform base + lane*16.
DEVFN void gld_lds16(const void* g, void* l) {
  __builtin_amdgcn_global_load_lds(
      (const __attribute__((address_space(1))) unsigned*)g,
      (__attribute__((address_space(3))) unsigned*)l, 16, 0, 0);
}

// ---------------------------------------------------------------- fused fp32->bf16
// One kernel casts all three inputs; destinations are contiguous in ws
// (xb | wqb | wob), so dst indexes by the global group id directly.
constexpr int G_X = 8192 * 1024 / 8;   // 1048576 groups of 8
constexpr int G_WQ = 3072 * 1024 / 8;  // 393216
constexpr int G_WO = 1024 * 1024 / 8;  // 131072
__global__ __launch_bounds__(256) void cast3_kernel(
    const float* __restrict__ x, const float* __restrict__ wq,
    const float* __restrict__ wo, short* __restrict__ dst) {
  const int i = blockIdx.x * 256 + threadIdx.x;
  const float* src;
  int rel;
  if (i < G_X) {
    src = x; rel = i;
  } else if (i < G_X + G_WQ) {
    src = wq; rel = i - G_X;
  } else {
    src = wo; rel = i - (G_X + G_WQ);
  }
  const floatx4* p = (const floatx4*)src + (size_t)rel * 2;
  floatx4 a = p[0], b = p[1];
  short8 r;
  r[0] = f2bf(a[0]); r[1] = f2bf(a[1]); r[2] = f2bf(a[2]); r[3] = f2bf(a[3]);
  r[4] = f2bf(b[0]); r[5] = f2bf(b[1]); r[6] = f2bf(b[2]); r[7] = f2bf(b[3]);
  ((short8*)dst)[i] = r;
}

// ================================================================ QKV GEMM
// 256x256 tile, BK=64, 8 waves (512 thr, 2M x 4N), 8-phase schedule with
// counted vmcnt (T3+T4) + setprio (T5) on top of the XOR-swizzled LDS (T2).
// Why: the previous 128x128 2-phase kernel sat at 669 TF / MfmaUtil 28.5%
// with conflicts==0 and HBM at 8.5% -- structure-bound on the per-K-step
// vmcnt(0)+barrier drain. The 8-phase schedule keeps 3 half-tiles (6
// global_load_lds) in flight ACROSS barriers; vmcnt is never drained to 0
// in the main loop.
//
// Geometry: per-wave output 128x64 = acc[8][4] 16x16 frags at
//   row = mi*32 + wr*16, col = ni*64 + wc*16  (both halves LDS-contiguous:
//   af(mh) = A rows [mh*128,mh*128+128), bf(nh) = B rows [nh*128,...)).
// LDS: 2 buf x (A 256x64 + B 256x64) bf16 = 128 KiB; 1 block/CU.
//
// Phase plan per K-tile t (buf = t&1), MFMA quadrant = (mh,nh):
//   P1: read af0(8)+bf0(4); stage A-h1(t+1)->buf^1; MMA(0,0)
//   P2: read bf1(4);        stage A-h0(t+2)->buf;   MMA(0,1)
//   P3: read af1(8);        stage B-h0(t+2)->buf;   MMA(1,0)
//   P4:                     stage B-h1(t+2)->buf;   MMA(1,1); vmcnt(6); bar
// Region-free invariants: A-h0/B-h0 last LDS-read at P1, B-h1 at P2,
// A-h1 at P3 -> every stage lands in a region whose readers passed a
// barrier. vmcnt(6) at P4-end retires everything except the P2/P3/P4
// stages (= 6 loads of tile t+2), i.e. exactly through A-h1(t+1): tile
// t+1 is fully in LDS before its first read. Prologue issues tile0 (8
// loads) + 3 half-tiles of tile1 (6 loads), then vmcnt(6) -> same state.
#define FENCE() __asm__ volatile("" ::: "memory")
#define BAR8() { FENCE(); __builtin_amdgcn_s_barrier(); FENCE(); }
#define VMW(n) __asm__ volatile("s_waitcnt vmcnt(" #n ")" ::: "memory")

__global__ __launch_bounds__(512, 2) void gemm_qkv(
    const short* __restrict__ A, const short* __restrict__ Bw,
    short* __restrict__ qkb, short* __restrict__ vtb) {
  __shared__ __align__(16) short As[2][256 * 64];  // 64 KB
  __shared__ __align__(16) short Bs[2][256 * 64];  // 64 KB

  const int tid = threadIdx.x;
  const int lane = tid & 63;
  const int wave = tid >> 6;
  const int l15 = lane & 15, quad = lane >> 4;
  const int wr = wave >> 2, wc = wave & 3;

  // Bijective XCD swizzle (384 blocks, 384%8==0): one XCD gets 48
  // consecutive wg = ~1.5 N-columns -> B panels (512KB) L2-resident.
  const int orig = blockIdx.y * 32 + blockIdx.x;
  const int wg = (orig & 7) * 48 + (orig >> 3);
  const int m0 = (wg & 31) * 256, n0 = (wg >> 5) * 256;

  // Stager: thread t covers row r0=t>>3 (+64 for 2nd load), 16B chunk
  // cs=t&7; XOR swizzle applied on the GLOBAL chunk ((r+64)&7 == r&7, so
  // one per-thread base works for both loads and all tiles/halves).
  const int r0 = tid >> 3, cs = tid & 7;
  const short* Ag = A + (size_t)(m0 + r0) * 1024 + (cs ^ (r0 & 7)) * 8;
  const short* Bg = Bw + (size_t)(n0 + r0) * 1024 + (cs ^ (r0 & 7)) * 8;
  short* Asl = (short*)As + tid * 8;  // + buf*16384 + h*8192 (+4096 2nd load)
  short* Bsl = (short*)Bs + tid * 8;

#define STG(ls, gp, buf_, tile_, h_)                                    \
  {                                                                     \
    gld_lds16(gp + (tile_) * 64 + (size_t)((h_) * 128) * 1024,          \
              ls + (buf_) * 16384 + (h_) * 8192);                       \
    gld_lds16(gp + (tile_) * 64 + (size_t)((h_) * 128 + 64) * 1024,     \
              ls + (buf_) * 16384 + (h_) * 8192 + 4096);                \
  }

  short8 af[4][2];      // one A-half (overwritten at P3)
  short8 bf[2][2][2];   // both B-halves live across the 4 phases
  floatx4 acc[8][4] = {};

#define RDA(mh_, buf_)                                                        \
  _Pragma("unroll") for (int mi = 0; mi < 4; ++mi)                            \
  _Pragma("unroll") for (int ks = 0; ks < 2; ++ks)                            \
      af[mi][ks] = *(const short8*)(                                          \
          (const short*)As + (buf_) * 16384 +                                 \
          (((mh_) * 4 + mi) * 32 + wr * 16 + l15) * 64 +                      \
          ((ks * 4 + quad) ^ (l15 & 7)) * 8);

#define RDB(nh_, buf_)                                                        \
  _Pragma("unroll") for (int ni = 0; ni < 2; ++ni)                            \
  _Pragma("unroll") for (int ks = 0; ks < 2; ++ks)                            \
      bf[nh_][ni][ks] = *(const short8*)(                                     \
          (const short*)Bs + (buf_) * 16384 +                                 \
          (((nh_) * 2 + ni) * 64 + wc * 16 + l15) * 64 +                      \
          ((ks * 4 + quad) ^ (l15 & 7)) * 8);

#define MMA(mh_, nh_)                                                         \
  __builtin_amdgcn_s_setprio(1);                                              \
  _Pragma("unroll") for (int mi = 0; mi < 4; ++mi)                            \
  _Pragma("unroll") for (int ni = 0; ni < 2; ++ni)                            \
  _Pragma("unroll") for (int ks = 0; ks < 2; ++ks)                            \
      acc[(mh_) * 4 + mi][(nh_) * 2 + ni] = mfma16(                           \
          af[mi][ks], bf[nh_][ni][ks], acc[(mh_) * 4 + mi][(nh_) * 2 + ni]);  \
  __builtin_amdgcn_s_setprio(0);

  // ---- prologue: tile0 complete + tile1 {A-h0, B-h0, B-h1}
  STG(Asl, Ag, 0, 0, 0) STG(Asl, Ag, 0, 0, 1)
  STG(Bsl, Bg, 0, 0, 0) STG(Bsl, Bg, 0, 0, 1)
  STG(Asl, Ag, 1, 1, 0) STG(Bsl, Bg, 1, 1, 0) STG(Bsl, Bg, 1, 1, 1)
  VMW(6);  // tile0 landed; tile1's 3 half-tiles stay in flight
  BAR8();

  // ---- main loop: 7 iterations x 2 K-tiles; tail (tiles 14,15) peeled so
  // the hot body has no branches.
#pragma unroll 1
  for (int tp = 0; tp < 7; ++tp) {
    const int t2 = 2 * tp + 2, t3 = 2 * tp + 3;
    // tile t0 = 2*tp  (buf 0)
    RDA(0, 0) RDB(0, 0) STG(Asl, Ag, 1, 2 * tp + 1, 1)
    BAR8(); MMA(0, 0) BAR8();
    RDB(1, 0) STG(Asl, Ag, 0, t2, 0)
    BAR8(); MMA(0, 1) BAR8();
    RDA(1, 0) STG(Bsl, Bg, 0, t2, 0)
    BAR8(); MMA(1, 0) BAR8();
    STG(Bsl, Bg, 0, t2, 1)
    BAR8(); MMA(1, 1) VMW(6); BAR8();
    // tile t1 = 2*tp+1  (buf 1)
    RDA(0, 1) RDB(0, 1) STG(Asl, Ag, 0, t2, 1)
    BAR8(); MMA(0, 0) BAR8();
    RDB(1, 1) STG(Asl, Ag, 1, t3, 0)
    BAR8(); MMA(0, 1) BAR8();
    RDA(1, 1) STG(Bsl, Bg, 1, t3, 0)
    BAR8(); MMA(1, 0) BAR8();
    STG(Bsl, Bg, 1, t3, 1)
    BAR8(); MMA(1, 1) VMW(6); BAR8();
  }
  // ---- tail: tile 14 (buf 0) -- only A-h1(15) left to stage
  RDA(0, 0) RDB(0, 0) STG(Asl, Ag, 1, 15, 1)
  BAR8(); MMA(0, 0) BAR8();
  RDB(1, 0)
  BAR8(); MMA(0, 1) BAR8();
  RDA(1, 0)
  BAR8(); MMA(1, 0) BAR8();
  MMA(1, 1) VMW(0); BAR8();
  // tile 15 (buf 1), nothing in flight
  RDA(0, 1) RDB(0, 1)
  BAR8(); MMA(0, 0) BAR8();
  RDB(1, 1)
  BAR8(); MMA(0, 1) BAR8();
  RDA(1, 1)
  BAR8(); MMA(1, 0) BAR8();
  MMA(1, 1)

  // ---- epilogue (MODE-0 semantics, same as the old 128x128 kernel).
  // C/D layout: col = lane&15, row = quad*4 + reg  [m89/m91].
#pragma unroll
  for (int mi = 0; mi < 8; ++mi) {
    const int row0 = m0 + mi * 32 + wr * 16 + quad * 4;
#pragma unroll
    for (int ni = 0; ni < 4; ++ni) {
      const int col = n0 + ni * 64 + wc * 16 + l15;
      if (col < 2 * Cn) {  // wave-uniform (band is 16 wide, 64-aligned)
#pragma unroll
        for (int r = 0; r < 4; ++r) {
          float v = acc[mi][ni][r];
          if (col < Cn) v *= SCL;  // softmax scale folded into Q
          qkb[(size_t)(row0 + r) * (2 * Cn) + col] = f2bf(v);
        }
      } else {
        const int hc = col - 2 * Cn;
        const int hh = hc >> 6, d = hc & 63;
        const int bb = row0 >> 11, t = row0 & (Tn - 1);
        uint2v pk;
        pk[0] = f2bf_u(acc[mi][ni][0]) | (f2bf_u(acc[mi][ni][1]) << 16);
        pk[1] = f2bf_u(acc[mi][ni][2]) | (f2bf_u(acc[mi][ni][3]) << 16);
        *(uint2v*)(vtb + ((size_t)((bb * Hn + hh) * Dn + d)) * Tn + t) = pk;
      }
    }
  }
#undef STG
#undef RDA
#undef RDB
#undef MMA
}

// ---------------------------------------------------------------- GEMM  Y = A @ B^T
// (kept for the output projection only; QKV now uses gemm_qkv above)
// BK=64 with XOR-swizzled LDS (16B chunk ^= row&7) applied on the stager's
// GLOBAL address, so fragment b128 reads are conflict-free while the LDS
// side keeps gld_lds16's required uniform+lane*16 mapping.
// MODE 1: output projection: fp32 out + bias.
template <int MODE>
__global__ __launch_bounds__(256, 2) void gemm_bt(
    const short* __restrict__ A, const short* __restrict__ Bw, int M, int N, int K,
    short* __restrict__ qkb, short* __restrict__ vtb,
    const float* __restrict__ bias, float* __restrict__ fout) {
  __shared__ short As[128 * 64];  // 16 KB, [row][chunk^(row&7)] of 8-short chunks
  __shared__ short Bs[128 * 64];
  const int tid = threadIdx.x;
  const int lane = tid & 63, wave = tid >> 6;
  const int l15 = lane & 15, quad = lane >> 4;
  const int wr = wave >> 1, wc = wave & 1;
  const int m0 = blockIdx.x * 128, n0 = blockIdx.y * 128;

  const int r0 = tid >> 3, cs = tid & 7;
  const short* Ag = A + (size_t)(m0 + r0) * K + (cs ^ (r0 & 7)) * 8;
  const short* Bg = Bw + (size_t)(n0 + r0) * K + (cs ^ (r0 & 7)) * 8;

  floatx4 acc[4][4] = {};

  for (int k0 = 0; k0 < K; k0 += 64) {
#pragma unroll
    for (int it = 0; it < 4; ++it) {
      gld_lds16(Ag + k0 + (size_t)(it * 32) * K, As + it * 2048 + tid * 8);
      gld_lds16(Bg + k0 + (size_t)(it * 32) * K, Bs + it * 2048 + tid * 8);
    }
    __syncthreads();
#pragma unroll
    for (int ks = 0; ks < 2; ++ks) {
      short8 af[4], bf[4];
#pragma unroll
      for (int i = 0; i < 4; ++i) {
        const int row = wr * 64 + i * 16 + l15;
        af[i] = *(const short8*)(As + row * 64 +
                                 ((ks * 4 + quad) ^ (l15 & 7)) * 8);
      }
#pragma unroll
      for (int i = 0; i < 4; ++i) {
        const int row = wc * 64 + i * 16 + l15;
        bf[i] = *(const short8*)(Bs + row * 64 +
                                 ((ks * 4 + quad) ^ (l15 & 7)) * 8);
      }
#pragma unroll
      for (int mi = 0; mi < 4; ++mi)
#pragma unroll
        for (int ni = 0; ni < 4; ++ni)
          acc[mi][ni] = mfma16(af[mi], bf[ni], acc[mi][ni]);
    }
    __syncthreads();
  }

#pragma unroll
  for (int mi = 0; mi < 4; ++mi) {
    const int row0 = m0 + wr * 64 + mi * 16 + quad * 4;
#pragma unroll
    for (int ni = 0; ni < 4; ++ni) {
      const int col = n0 + wc * 64 + ni * 16 + l15;
      if constexpr (MODE == 0) {
        if (col < 2 * Cn) {
#pragma unroll
          for (int r = 0; r < 4; ++r) {
            float v = acc[mi][ni][r];
            if (col < Cn) v *= SCL;
            qkb[(size_t)(row0 + r) * (2 * Cn) + col] = f2bf(v);
          }
        } else {
          const int hc = col - 2 * Cn;
          const int hh = hc >> 6, d = hc & 63;
          const int bb = row0 >> 11, t = row0 & (Tn - 1);
          uint2v pk;
          pk[0] = f2bf_u(acc[mi][ni][0]) | (f2bf_u(acc[mi][ni][1]) << 16);
          pk[1] = f2bf_u(acc[mi][ni][2]) | (f2bf_u(acc[mi][ni][3]) << 16);
          *(uint2v*)(vtb + ((size_t)((bb * Hn + hh) * Dn + d)) * Tn + t) = pk;
        }
      } else {
#pragma unroll
        for (int r = 0; r < 4; ++r)
          fout[(size_t)(row0 + r) * N + col] = acc[mi][ni][r] + bias[col];
      }
    }
  }
}

// ---------------------------------------------------------------- flash attention
// Block = 4 waves; wave owns 32 Q rows (2 i-frags). KV tile = 64, double-
// buffered LDS via async global_load_lds, ONE barrier per tile. XOR-swizzled
// LDS layouts (16B chunk ^= row&7) applied on the stager's GLOBAL address.
// Transposed math: S^T = K.Q^T, O^T = V^T.P^T; no online max; per-lane row
// sums reduced once at the end. P round-trip through per-wave 2KB LDS is done
// PER i-frag (LDS 40KB -> 4 blocks/CU).
// Grid dim3(64,16): bh = x, qt = 15-y. Linear id = bh + 64*(15-qt) gives
//   (a) globally DESCENDING qt (long blocks dispatch first -> balanced tail),
//   (b) id%8 = bh%8 -> all blocks of one bh on one XCD (L2 keeps its K/V).
// launch_bounds(256,3): VGPR cap 170 -- (256,4) forced 64 VGPRs and spilled
// ~217 MB of scratch to HBM (R4 WRITE_SIZE smoking gun). Don't tighten it.
__global__ __launch_bounds__(256, 3) void attn_kernel(
    const short* __restrict__ qk, const short* __restrict__ vt,
    short* __restrict__ att) {
  __shared__ short Ks[2][64 * 64];
  __shared__ short Vs[2][64 * 64];
  __shared__ short Ps[4][16 * 64];  // per-wave P-frag scratch (2 KB)

  const int bh = blockIdx.x;       // 0..63
  const int qt = 15 - blockIdx.y;  // globally longest-first
  const int b = bh >> 4, h = bh & 15;
  const int tid = threadIdx.x;
  const int lane = tid & 63, wave = tid >> 6;
  const int l15 = lane & 15, quad = lane >> 4;
  const int q0w = qt * 128 + wave * 32;  // this wave's 32 Q rows

  const short* qbase = qk + (size_t)(b * Tn) * 2048 + h * 64;
  const short* kbase = qbase + 1024;
  const short* vbase = vt + (size_t)(bh * 64) * Tn;
  short* pw = Ps[wave];

  // Q^T fragments (B-operand rows [i][c]) in registers for the whole kernel.
  short8 qf[2][2];
#pragma unroll
  for (int f = 0; f < 2; ++f)
#pragma unroll
    for (int ks = 0; ks < 2; ++ks)
      qf[f][ks] = *(const short8*)(qbase + (size_t)(q0w + f * 16 + l15) * 2048 +
                                   ks * 32 + quad * 8);

  floatx4 o[2][4] = {};         // O^T accumulator [f][nd], C-layout (row=d, col=i)
  float lpart[2] = {0.f, 0.f};  // per-lane row sums (i = l15)

  const int wave_nt = ((q0w + 31) >> 6) + 1;  // tiles this wave computes
  const int block_nt = 2 * qt + 2;            // loop count (uniform per block)

  const int jr = tid >> 3;  // staging row 0..31 (+32 on 2nd pass)
  const int cl = tid & 7;   // staging LDS chunk

#define STAGE(JT, BUF)                                                       \
  {                                                                          \
    const int j0s = (JT) * 64;                                               \
    _Pragma("unroll") for (int it = 0; it < 2; ++it) {                       \
      const int row = jr + it * 32;                                          \
      const int cg = cl ^ (row & 7);                                         \
      gld_lds16(kbase + (size_t)(j0s + row) * 2048 + cg * 8,                 \
                &Ks[BUF][it * 2048 + tid * 8]);                              \
      gld_lds16(vbase + (size_t)row * Tn + j0s + cg * 8,                     \
                &Vs[BUF][it * 2048 + tid * 8]);                              \
    }                                                                        \
  }

  STAGE(0, 0)
  __syncthreads();

  for (int jt = 0; jt < block_nt; ++jt) {
    const int buf = jt & 1;
    if (jt + 1 < block_nt) STAGE(jt + 1, buf ^ 1)

    if (jt < wave_nt) {
      const int j0 = jt * 64;

      // ---- S^T = K.Q^T for both i-frags; kf in 2 batches (VGPR economy)
      floatx4 st[2][4];
#pragma unroll
      for (int f = 0; f < 2; ++f)
#pragma unroll
        for (int nj = 0; nj < 4; ++nj) st[f][nj] = floatx4{0.f, 0.f, 0.f, 0.f};
#pragma unroll
      for (int half = 0; half < 2; ++half) {
        short8 kfa[2][2];
#pragma unroll
        for (int j2 = 0; j2 < 2; ++j2)
#pragma unroll
          for (int ks = 0; ks < 2; ++ks) {
            const int cld = (ks * 4 + quad) ^ (l15 & 7);
            kfa[j2][ks] = *(const short8*)(
                &Ks[buf][((half * 2 + j2) * 16 + l15) * 64 + cld * 8]);
          }
#pragma unroll
        for (int f = 0; f < 2; ++f)
#pragma unroll
          for (int j2 = 0; j2 < 2; ++j2)
#pragma unroll
            for (int ks = 0; ks < 2; ++ks)
              st[f][half * 2 + j2] =
                  mfma16(kfa[j2][ks], qf[f][ks], st[f][half * 2 + j2]);
      }

      // ---- V^T fragments (A-operand rows [d][j]), shared by both i-frags
      short8 vf[4][2];
#pragma unroll
      for (int nd = 0; nd < 4; ++nd)
#pragma unroll
        for (int ks = 0; ks < 2; ++ks) {
          const int cld = (ks * 4 + quad) ^ (l15 & 7);
          vf[nd][ks] =
              *(const short8*)(&Vs[buf][(nd * 16 + l15) * 64 + cld * 8]);
        }

      // ---- per i-frag: exp -> P -> LDS -> PV  (2KB per-wave scratch)
#pragma unroll
      for (int f = 0; f < 2; ++f) {
        const bool need_mask = (j0 + 63 > q0w + f * 16);
        const int ig = q0w + f * 16 + l15;
#pragma unroll
        for (int nj = 0; nj < 4; ++nj) {
          float p[4];
#pragma unroll
          for (int r = 0; r < 4; ++r) {
            float e = __builtin_amdgcn_exp2f(st[f][nj][r]);
            if (need_mask) {
              const int jg = j0 + nj * 16 + quad * 4 + r;
              e = (jg > ig) ? 0.f : e;
            }
            lpart[f] += e;
            p[r] = e;
          }
          // rows j = nj*16+quad*4 .. +3 are consecutive -> one b64 write
          const int c = nj * 2 + (quad >> 1);
          const int cld = c ^ (l15 & 7);
          uint2v pk;
          pk[0] = f2bf_u(p[0]) | (f2bf_u(p[1]) << 16);
          pk[1] = f2bf_u(p[2]) | (f2bf_u(p[3]) << 16);
          *(uint2v*)(&pw[l15 * 64 + cld * 8 + (quad & 1) * 4]) = pk;
        }
        // wave-local: drain P writes (lanes lockstep; DS ops in-order)
        __asm__ volatile("s_waitcnt lgkmcnt(0)" ::: "memory");

        short8 pf[2];
#pragma unroll
        for (int ks = 0; ks < 2; ++ks) {
          const int cld = (ks * 4 + quad) ^ (l15 & 7);
          pf[ks] = *(const short8*)(&pw[l15 * 64 + cld * 8]);
        }
#pragma unroll
        for (int nd = 0; nd < 4; ++nd)
#pragma unroll
          for (int ks = 0; ks < 2; ++ks)
            o[f][nd] = mfma16(vf[nd][ks], pf[ks], o[f][nd]);
        __asm__ volatile("" ::: "memory");  // keep f=1 P writes after pf reads
      }
    }
    __syncthreads();
  }

  // ---- final row sums: i = l15 -> only 2 cross-quad shuffles per frag
  float inv[2];
#pragma unroll
  for (int f = 0; f < 2; ++f) {
    float s2 = lpart[f];
    s2 += __shfl_xor(s2, 16);
    s2 += __shfl_xor(s2, 32);
    inv[f] = 1.0f / s2;
  }

  // ---- un-transpose O via per-wave LDS (16x64 per pass), coalesced stores
#pragma unroll
  for (int f = 0; f < 2; ++f) {
#pragma unroll
    for (int nd = 0; nd < 4; ++nd) {
      const int c = nd * 2 + (quad >> 1);
      const int cld = c ^ (l15 & 7);
      uint2v pk;
      pk[0] =
          f2bf_u(o[f][nd][0] * inv[f]) | (f2bf_u(o[f][nd][1] * inv[f]) << 16);
      pk[1] =
          f2bf_u(o[f][nd][2] * inv[f]) | (f2bf_u(o[f][nd][3] * inv[f]) << 16);
      *(uint2v*)(&pw[l15 * 64 + cld * 8 + (quad & 1) * 4]) = pk;
    }
    __asm__ volatile("s_waitcnt lgkmcnt(0)" ::: "memory");
#pragma unroll
    for (int ps = 0; ps < 2; ++ps) {
      const int r16 = ps * 8 + (lane >> 3);  // 0..15
      const int cn = lane & 7;
      const int cldr = cn ^ (r16 & 7);
      const short8 val = *(const short8*)(&pw[r16 * 64 + cldr * 8]);
      *(short8*)(att + (size_t)(b * Tn + q0w + f * 16 + r16) * Cn + h * 64 +
                 cn * 8) = val;
    }
    __asm__ volatile("" ::: "memory");  // f=1 writes stay after f=0 reads
  }
#undef STAGE
}

// ---------------------------------------------------------------- launch
extern "C" void kernel_launch(void* const* d_in, const int* in_sizes, int n_in,
                              void* d_out, int out_size, void* d_ws,
                              size_t ws_size, hipStream_t stream) {
  const float* x = (const float*)d_in[0];      // [B,T,C]
  const float* w_qkv = (const float*)d_in[1];  // [3C,C]
  const float* w_out = (const float*)d_in[2];  // [C,C]
  const float* b_out = (const float*)d_in[3];  // [C]
  float* out = (float*)d_out;                  // [B,T,C] fp32

  // Workspace layout (75.5 MB total):
  short* xb = (short*)d_ws;                      // 8192*1024  x bf16
  short* wqb = xb + (size_t)8192 * 1024;         // 3072*1024  w_qkv bf16
  short* wob = wqb + (size_t)3072 * 1024;        // 1024*1024  w_out bf16
  short* qkb = wob + (size_t)1024 * 1024;        // 8192*2048  q|k bf16 (q pre-scaled)
  short* vtb = qkb + (size_t)8192 * 2048;        // 64*64*2048 v transposed
  short* att = xb;  // x is dead after GEMM1; reuse for attention output

  // One fused cast: dst segments (xb|wqb|wob) are contiguous in ws.
  cast3_kernel<<<dim3((G_X + G_WQ + G_WO) / 256), 256, 0, stream>>>(
      x, w_qkv, w_out, xb);

  // QKV projection: M=8192, N=3072, K=1024 -- 256^2 8-phase kernel
  gemm_qkv<<<dim3(32, 12), 512, 0, stream>>>(xb, wqb, qkb, vtb);
  // Flash attention: bh = x (XCD-affine), qt descending globally
  attn_kernel<<<dim3(64, 16), 256, 0, stream>>>(qkb, vtb, att);
  // Output projection: M=8192, N=1024, K=1024, +bias, fp32 out
  gemm_bt<1><<<dim3(64, 8), 256, 0, stream>>>(att, wob, 8192, 1024, 1024,
                                              nullptr, nullptr, b_out, out);
}

// Round 4
// 243.081 us; speedup vs baseline: 1.0483x; 1.0483x over previous
//
#include <hip/hip_runtime.h>

// Problem constants (B,T,C,H fixed by the reference).
constexpr int Bn = 4, Tn = 2048, Cn = 1024, Hn = 16, Dn = 64;

typedef __attribute__((ext_vector_type(8))) short short8;
typedef __attribute__((ext_vector_type(4))) float floatx4;
typedef __attribute__((ext_vector_type(2))) unsigned uint2v;

#define DEVFN __device__ __forceinline__

// exp(s/8) = exp2(s * log2e/8); folded into Q at GEMM1 epilogue.
constexpr float SCL = 0.18033688011112042f;

// RTNE float -> bf16 raw bits (inputs are finite; no NaN handling needed).
DEVFN unsigned f2bf_u(float f) {
  unsigned u = __builtin_bit_cast(unsigned, f);
  u += 0x7fffu + ((u >> 16) & 1u);
  return u >> 16;
}
DEVFN short f2bf(float f) { return (short)f2bf_u(f); }

DEVFN floatx4 mfma16(short8 a, short8 b, floatx4 c) {
  return __builtin_amdgcn_mfma_f32_16x16x32_bf16(a, b, c, 0, 0, 0);
}

// Async global->LDS, 16B/lane. LDS dest must be wave-uniform base + lane*16.
DEVFN void gld_lds16(const void* g, void* l) {
  __builtin_amdgcn_global_load_lds(
      (const __attribute__((address_space(1))) unsigned*)g,
      (__attribute__((address_space(3))) unsigned*)l, 16, 0, 0);
}

// ---------------------------------------------------------------- fused fp32->bf16
// One kernel casts all three inputs; destinations are contiguous in ws
// (xb | wqb | wob), so dst indexes by the global group id directly.
constexpr int G_X = 8192 * 1024 / 8;   // 1048576 groups of 8
constexpr int G_WQ = 3072 * 1024 / 8;  // 393216
constexpr int G_WO = 1024 * 1024 / 8;  // 131072
__global__ __launch_bounds__(256) void cast3_kernel(
    const float* __restrict__ x, const float* __restrict__ wq,
    const float* __restrict__ wo, short* __restrict__ dst) {
  const int i = blockIdx.x * 256 + threadIdx.x;
  const float* src;
  int rel;
  if (i < G_X) {
    src = x; rel = i;
  } else if (i < G_X + G_WQ) {
    src = wq; rel = i - G_X;
  } else {
    src = wo; rel = i - (G_X + G_WQ);
  }
  const floatx4* p = (const floatx4*)src + (size_t)rel * 2;
  floatx4 a = p[0], b = p[1];
  short8 r;
  r[0] = f2bf(a[0]); r[1] = f2bf(a[1]); r[2] = f2bf(a[2]); r[3] = f2bf(a[3]);
  r[4] = f2bf(b[0]); r[5] = f2bf(b[1]); r[6] = f2bf(b[2]); r[7] = f2bf(b[3]);
  ((short8*)dst)[i] = r;
}

// ================================================================ QKV GEMM
// 256x256 tile, BK=64, 8 waves (512 thr, 2M x 4N), 8-phase schedule with
// counted vmcnt (T3+T4) + setprio (T5) on top of the XOR-swizzled LDS (T2).
//
// R1 post-mortem: the schedule worked (passed, conflicts 0) but the first
// XCD swizzle gave each XCD a full N-column -> every XCD streamed the whole
// 16.8MB A through its 4MB L2 -> FETCH_SIZE 103.6MB (4.5x input) at 1.9TB/s,
// and the 3-phase-deep vmcnt(6) pipeline (~600cy) couldn't hide HBM misses
// (~900cy): MfmaUtil 23%. Fix: m-CHUNKED swizzle -- each XCD owns 4
// contiguous m-panels (2MB of A, L2-resident, disjoint across XCDs; A is
// fetched from HBM once); the 4 co-resident blocks of an XCD share one
// B-panel (512KB) -> 2.5MB working set < 4MB L2; B overall L3-resident.
// (R2/R3 benches died in the container broker -- no kernel-side mechanism
// found in a full control-flow/bounds/race re-audit; swizzle re-expressed
// with a shift/mask grid dim3(8,48) as a build hedge, same experiment.)
//
// Geometry: per-wave output 128x64 = acc[8][4] 16x16 frags at
//   row = mi*32 + wr*16, col = ni*64 + wc*16.
// LDS: 2 buf x (A 256x64 + B 256x64) bf16 = 128 KiB; 1 block/CU.
//
// Phase plan per K-tile t (buf = t&1), MFMA quadrant = (mh,nh):
//   P1: read af0(8)+bf0(4); stage A-h1(t+1)->buf^1; MMA(0,0)
//   P2: read bf1(4);        stage A-h0(t+2)->buf;   MMA(0,1)
//   P3: read af1(8);        stage B-h0(t+2)->buf;   MMA(1,0)
//   P4:                     stage B-h1(t+2)->buf;   MMA(1,1); vmcnt(6); bar
// vmcnt retires in order, so waiting to 6 at P4 retires everything except
// the P2/P3/P4 stages (tile t+2's three half-tiles) -> tile t+1 fully in
// LDS before its first read. Prologue: tile0 (8 loads) + 3 half-tiles of
// tile1 (6 loads), vmcnt(6) -> same steady state.
#define FENCE() __asm__ volatile("" ::: "memory")
#define BAR8() { FENCE(); __builtin_amdgcn_s_barrier(); FENCE(); }
#define VMW(n) __asm__ volatile("s_waitcnt vmcnt(" #n ")" ::: "memory")

__global__ __launch_bounds__(512, 2) void gemm_qkv(
    const short* __restrict__ A, const short* __restrict__ Bw,
    short* __restrict__ qkb, short* __restrict__ vtb) {
  __shared__ __align__(16) short As[2][256 * 64];  // 64 KB
  __shared__ __align__(16) short Bs[2][256 * 64];  // 64 KB

  const int tid = threadIdx.x;
  const int lane = tid & 63;
  const int wave = tid >> 6;
  const int l15 = lane & 15, quad = lane >> 4;
  const int wr = wave >> 2, wc = wave & 3;

  // m-chunked bijective XCD swizzle, shift/mask form. Grid dim3(8,48):
  // linear id = bx + 8*by -> XCD = bx. XCD owns m-panels [bx*4, bx*4+4);
  // m iterates fastest (by&3), n advances every 4 blocks (by>>2).
  const int xcd = blockIdx.x, by = blockIdx.y;
  const int mp = (xcd << 2) + (by & 3);  // m-panel 0..31
  const int np = by >> 2;                // n-panel 0..11
  const int m0 = mp * 256, n0 = np * 256;

  // Stager: thread t covers row r0=t>>3 (+64 for 2nd load), 16B chunk
  // cs=t&7; XOR swizzle applied on the GLOBAL chunk ((r+64)&7 == r&7, so
  // one per-thread base works for both loads and all tiles/halves).
  const int r0 = tid >> 3, cs = tid & 7;
  const short* Ag = A + (size_t)(m0 + r0) * 1024 + (cs ^ (r0 & 7)) * 8;
  const short* Bg = Bw + (size_t)(n0 + r0) * 1024 + (cs ^ (r0 & 7)) * 8;
  short* Asl = (short*)As + tid * 8;  // + buf*16384 + h*8192 (+4096 2nd load)
  short* Bsl = (short*)Bs + tid * 8;

#define STG(ls, gp, buf_, tile_, h_)                                    \
  {                                                                     \
    gld_lds16(gp + (tile_) * 64 + (size_t)((h_) * 128) * 1024,          \
              ls + (buf_) * 16384 + (h_) * 8192);                       \
    gld_lds16(gp + (tile_) * 64 + (size_t)((h_) * 128 + 64) * 1024,     \
              ls + (buf_) * 16384 + (h_) * 8192 + 4096);                \
  }

  short8 af[4][2];      // one A-half (overwritten at P3)
  short8 bf[2][2][2];   // both B-halves live across the 4 phases
  floatx4 acc[8][4] = {};

#define RDA(mh_, buf_)                                                        \
  _Pragma("unroll") for (int mi = 0; mi < 4; ++mi)                            \
  _Pragma("unroll") for (int ks = 0; ks < 2; ++ks)                            \
      af[mi][ks] = *(const short8*)(                                          \
          (const short*)As + (buf_) * 16384 +                                 \
          (((mh_) * 4 + mi) * 32 + wr * 16 + l15) * 64 +                      \
          ((ks * 4 + quad) ^ (l15 & 7)) * 8);

#define RDB(nh_, buf_)                                                        \
  _Pragma("unroll") for (int ni = 0; ni < 2; ++ni)                            \
  _Pragma("unroll") for (int ks = 0; ks < 2; ++ks)                            \
      bf[nh_][ni][ks] = *(const short8*)(                                     \
          (const short*)Bs + (buf_) * 16384 +                                 \
          (((nh_) * 2 + ni) * 64 + wc * 16 + l15) * 64 +                      \
          ((ks * 4 + quad) ^ (l15 & 7)) * 8);

#define MMA(mh_, nh_)                                                         \
  __builtin_amdgcn_s_setprio(1);                                              \
  _Pragma("unroll") for (int mi = 0; mi < 4; ++mi)                            \
  _Pragma("unroll") for (int ni = 0; ni < 2; ++ni)                            \
  _Pragma("unroll") for (int ks = 0; ks < 2; ++ks)                            \
      acc[(mh_) * 4 + mi][(nh_) * 2 + ni] = mfma16(                           \
          af[mi][ks], bf[nh_][ni][ks], acc[(mh_) * 4 + mi][(nh_) * 2 + ni]);  \
  __builtin_amdgcn_s_setprio(0);

  // ---- prologue: tile0 complete + tile1 {A-h0, B-h0, B-h1}
  STG(Asl, Ag, 0, 0, 0) STG(Asl, Ag, 0, 0, 1)
  STG(Bsl, Bg, 0, 0, 0) STG(Bsl, Bg, 0, 0, 1)
  STG(Asl, Ag, 1, 1, 0) STG(Bsl, Bg, 1, 1, 0) STG(Bsl, Bg, 1, 1, 1)
  VMW(6);  // tile0 landed; tile1's 3 half-tiles stay in flight
  BAR8();

  // ---- main loop: 7 iterations x 2 K-tiles; tail (tiles 14,15) peeled so
  // the hot body has no branches.
#pragma unroll 1
  for (int tp = 0; tp < 7; ++tp) {
    const int t2 = 2 * tp + 2, t3 = 2 * tp + 3;
    // tile t0 = 2*tp  (buf 0)
    RDA(0, 0) RDB(0, 0) STG(Asl, Ag, 1, 2 * tp + 1, 1)
    BAR8(); MMA(0, 0) BAR8();
    RDB(1, 0) STG(Asl, Ag, 0, t2, 0)
    BAR8(); MMA(0, 1) BAR8();
    RDA(1, 0) STG(Bsl, Bg, 0, t2, 0)
    BAR8(); MMA(1, 0) BAR8();
    STG(Bsl, Bg, 0, t2, 1)
    BAR8(); MMA(1, 1) VMW(6); BAR8();
    // tile t1 = 2*tp+1  (buf 1)
    RDA(0, 1) RDB(0, 1) STG(Asl, Ag, 0, t2, 1)
    BAR8(); MMA(0, 0) BAR8();
    RDB(1, 1) STG(Asl, Ag, 1, t3, 0)
    BAR8(); MMA(0, 1) BAR8();
    RDA(1, 1) STG(Bsl, Bg, 1, t3, 0)
    BAR8(); MMA(1, 0) BAR8();
    STG(Bsl, Bg, 1, t3, 1)
    BAR8(); MMA(1, 1) VMW(6); BAR8();
  }
  // ---- tail: tile 14 (buf 0) -- only A-h1(15) left to stage
  RDA(0, 0) RDB(0, 0) STG(Asl, Ag, 1, 15, 1)
  BAR8(); MMA(0, 0) BAR8();
  RDB(1, 0)
  BAR8(); MMA(0, 1) BAR8();
  RDA(1, 0)
  BAR8(); MMA(1, 0) BAR8();
  MMA(1, 1) VMW(0); BAR8();
  // tile 15 (buf 1), nothing in flight
  RDA(0, 1) RDB(0, 1)
  BAR8(); MMA(0, 0) BAR8();
  RDB(1, 1)
  BAR8(); MMA(0, 1) BAR8();
  RDA(1, 1)
  BAR8(); MMA(1, 0) BAR8();
  MMA(1, 1)

  // ---- epilogue (MODE-0 semantics, same as the old 128x128 kernel).
  // C/D layout: col = lane&15, row = quad*4 + reg  [m89/m91].
#pragma unroll
  for (int mi = 0; mi < 8; ++mi) {
    const int row0 = m0 + mi * 32 + wr * 16 + quad * 4;
#pragma unroll
    for (int ni = 0; ni < 4; ++ni) {
      const int col = n0 + ni * 64 + wc * 16 + l15;
      if (col < 2 * Cn) {  // wave-uniform (band is 16 wide, 64-aligned)
#pragma unroll
        for (int r = 0; r < 4; ++r) {
          float v = acc[mi][ni][r];
          if (col < Cn) v *= SCL;  // softmax scale folded into Q
          qkb[(size_t)(row0 + r) * (2 * Cn) + col] = f2bf(v);
        }
      } else {
        const int hc = col - 2 * Cn;
        const int hh = hc >> 6, d = hc & 63;
        const int bb = row0 >> 11, t = row0 & (Tn - 1);
        uint2v pk;
        pk[0] = f2bf_u(acc[mi][ni][0]) | (f2bf_u(acc[mi][ni][1]) << 16);
        pk[1] = f2bf_u(acc[mi][ni][2]) | (f2bf_u(acc[mi][ni][3]) << 16);
        *(uint2v*)(vtb + ((size_t)((bb * Hn + hh) * Dn + d)) * Tn + t) = pk;
      }
    }
  }
#undef STG
#undef RDA
#undef RDB
#undef MMA
}

// ---------------------------------------------------------------- GEMM  Y = A @ B^T
// (kept for the output projection only; QKV now uses gemm_qkv above)
// BK=64 with XOR-swizzled LDS (16B chunk ^= row&7) applied on the stager's
// GLOBAL address, so fragment b128 reads are conflict-free while the LDS
// side keeps gld_lds16's required uniform+lane*16 mapping.
// MODE 1: output projection: fp32 out + bias.
template <int MODE>
__global__ __launch_bounds__(256, 2) void gemm_bt(
    const short* __restrict__ A, const short* __restrict__ Bw, int M, int N, int K,
    short* __restrict__ qkb, short* __restrict__ vtb,
    const float* __restrict__ bias, float* __restrict__ fout) {
  __shared__ short As[128 * 64];  // 16 KB, [row][chunk^(row&7)] of 8-short chunks
  __shared__ short Bs[128 * 64];
  const int tid = threadIdx.x;
  const int lane = tid & 63, wave = tid >> 6;
  const int l15 = lane & 15, quad = lane >> 4;
  const int wr = wave >> 1, wc = wave & 1;
  const int m0 = blockIdx.x * 128, n0 = blockIdx.y * 128;

  const int r0 = tid >> 3, cs = tid & 7;
  const short* Ag = A + (size_t)(m0 + r0) * K + (cs ^ (r0 & 7)) * 8;
  const short* Bg = Bw + (size_t)(n0 + r0) * K + (cs ^ (r0 & 7)) * 8;

  floatx4 acc[4][4] = {};

  for (int k0 = 0; k0 < K; k0 += 64) {
#pragma unroll
    for (int it = 0; it < 4; ++it) {
      gld_lds16(Ag + k0 + (size_t)(it * 32) * K, As + it * 2048 + tid * 8);
      gld_lds16(Bg + k0 + (size_t)(it * 32) * K, Bs + it * 2048 + tid * 8);
    }
    __syncthreads();
#pragma unroll
    for (int ks = 0; ks < 2; ++ks) {
      short8 af[4], bf[4];
#pragma unroll
      for (int i = 0; i < 4; ++i) {
        const int row = wr * 64 + i * 16 + l15;
        af[i] = *(const short8*)(As + row * 64 +
                                 ((ks * 4 + quad) ^ (l15 & 7)) * 8);
      }
#pragma unroll
      for (int i = 0; i < 4; ++i) {
        const int row = wc * 64 + i * 16 + l15;
        bf[i] = *(const short8*)(Bs + row * 64 +
                                 ((ks * 4 + quad) ^ (l15 & 7)) * 8);
      }
#pragma unroll
      for (int mi = 0; mi < 4; ++mi)
#pragma unroll
        for (int ni = 0; ni < 4; ++ni)
          acc[mi][ni] = mfma16(af[mi], bf[ni], acc[mi][ni]);
    }
    __syncthreads();
  }

#pragma unroll
  for (int mi = 0; mi < 4; ++mi) {
    const int row0 = m0 + wr * 64 + mi * 16 + quad * 4;
#pragma unroll
    for (int ni = 0; ni < 4; ++ni) {
      const int col = n0 + wc * 64 + ni * 16 + l15;
      if constexpr (MODE == 0) {
        if (col < 2 * Cn) {
#pragma unroll
          for (int r = 0; r < 4; ++r) {
            float v = acc[mi][ni][r];
            if (col < Cn) v *= SCL;
            qkb[(size_t)(row0 + r) * (2 * Cn) + col] = f2bf(v);
          }
        } else {
          const int hc = col - 2 * Cn;
          const int hh = hc >> 6, d = hc & 63;
          const int bb = row0 >> 11, t = row0 & (Tn - 1);
          uint2v pk;
          pk[0] = f2bf_u(acc[mi][ni][0]) | (f2bf_u(acc[mi][ni][1]) << 16);
          pk[1] = f2bf_u(acc[mi][ni][2]) | (f2bf_u(acc[mi][ni][3]) << 16);
          *(uint2v*)(vtb + ((size_t)((bb * Hn + hh) * Dn + d)) * Tn + t) = pk;
        }
      } else {
#pragma unroll
        for (int r = 0; r < 4; ++r)
          fout[(size_t)(row0 + r) * N + col] = acc[mi][ni][r] + bias[col];
      }
    }
  }
}

// ---------------------------------------------------------------- flash attention
// Block = 4 waves; wave owns 32 Q rows (2 i-frags). KV tile = 64, double-
// buffered LDS via async global_load_lds, ONE barrier per tile. XOR-swizzled
// LDS layouts (16B chunk ^= row&7) applied on the stager's GLOBAL address.
// Transposed math: S^T = K.Q^T, O^T = V^T.P^T; no online max; per-lane row
// sums reduced once at the end. P round-trip through per-wave 2KB LDS is done
// PER i-frag (LDS 40KB -> 4 blocks/CU).
// Grid dim3(64,16): bh = x, qt = 15-y. Linear id = bh + 64*(15-qt) gives
//   (a) globally DESCENDING qt (long blocks dispatch first -> balanced tail),
//   (b) id%8 = bh%8 -> all blocks of one bh on one XCD (L2 keeps its K/V).
// launch_bounds(256,3): VGPR cap 170 -- (256,4) forced 64 VGPRs and spilled
// ~217 MB of scratch to HBM (R4 WRITE_SIZE smoking gun). Don't tighten it.
__global__ __launch_bounds__(256, 3) void attn_kernel(
    const short* __restrict__ qk, const short* __restrict__ vt,
    short* __restrict__ att) {
  __shared__ short Ks[2][64 * 64];
  __shared__ short Vs[2][64 * 64];
  __shared__ short Ps[4][16 * 64];  // per-wave P-frag scratch (2 KB)

  const int bh = blockIdx.x;       // 0..63
  const int qt = 15 - blockIdx.y;  // globally longest-first
  const int b = bh >> 4, h = bh & 15;
  const int tid = threadIdx.x;
  const int lane = tid & 63, wave = tid >> 6;
  const int l15 = lane & 15, quad = lane >> 4;
  const int q0w = qt * 128 + wave * 32;  // this wave's 32 Q rows

  const short* qbase = qk + (size_t)(b * Tn) * 2048 + h * 64;
  const short* kbase = qbase + 1024;
  const short* vbase = vt + (size_t)(bh * 64) * Tn;
  short* pw = Ps[wave];

  // Q^T fragments (B-operand rows [i][c]) in registers for the whole kernel.
  short8 qf[2][2];
#pragma unroll
  for (int f = 0; f < 2; ++f)
#pragma unroll
    for (int ks = 0; ks < 2; ++ks)
      qf[f][ks] = *(const short8*)(qbase + (size_t)(q0w + f * 16 + l15) * 2048 +
                                   ks * 32 + quad * 8);

  floatx4 o[2][4] = {};         // O^T accumulator [f][nd], C-layout (row=d, col=i)
  float lpart[2] = {0.f, 0.f};  // per-lane row sums (i = l15)

  const int wave_nt = ((q0w + 31) >> 6) + 1;  // tiles this wave computes
  const int block_nt = 2 * qt + 2;            // loop count (uniform per block)

  const int jr = tid >> 3;  // staging row 0..31 (+32 on 2nd pass)
  const int cl = tid & 7;   // staging LDS chunk

#define STAGE(JT, BUF)                                                       \
  {                                                                          \
    const int j0s = (JT) * 64;                                               \
    _Pragma("unroll") for (int it = 0; it < 2; ++it) {                       \
      const int row = jr + it * 32;                                          \
      const int cg = cl ^ (row & 7);                                         \
      gld_lds16(kbase + (size_t)(j0s + row) * 2048 + cg * 8,                 \
                &Ks[BUF][it * 2048 + tid * 8]);                              \
      gld_lds16(vbase + (size_t)row * Tn + j0s + cg * 8,                     \
                &Vs[BUF][it * 2048 + tid * 8]);                              \
    }                                                                        \
  }

  STAGE(0, 0)
  __syncthreads();

  for (int jt = 0; jt < block_nt; ++jt) {
    const int buf = jt & 1;
    if (jt + 1 < block_nt) STAGE(jt + 1, buf ^ 1)

    if (jt < wave_nt) {
      const int j0 = jt * 64;

      // ---- S^T = K.Q^T for both i-frags; kf in 2 batches (VGPR economy)
      floatx4 st[2][4];
#pragma unroll
      for (int f = 0; f < 2; ++f)
#pragma unroll
        for (int nj = 0; nj < 4; ++nj) st[f][nj] = floatx4{0.f, 0.f, 0.f, 0.f};
#pragma unroll
      for (int half = 0; half < 2; ++half) {
        short8 kfa[2][2];
#pragma unroll
        for (int j2 = 0; j2 < 2; ++j2)
#pragma unroll
          for (int ks = 0; ks < 2; ++ks) {
            const int cld = (ks * 4 + quad) ^ (l15 & 7);
            kfa[j2][ks] = *(const short8*)(
                &Ks[buf][((half * 2 + j2) * 16 + l15) * 64 + cld * 8]);
          }
#pragma unroll
        for (int f = 0; f < 2; ++f)
#pragma unroll
          for (int j2 = 0; j2 < 2; ++j2)
#pragma unroll
            for (int ks = 0; ks < 2; ++ks)
              st[f][half * 2 + j2] =
                  mfma16(kfa[j2][ks], qf[f][ks], st[f][half * 2 + j2]);
      }

      // ---- V^T fragments (A-operand rows [d][j]), shared by both i-frags
      short8 vf[4][2];
#pragma unroll
      for (int nd = 0; nd < 4; ++nd)
#pragma unroll
        for (int ks = 0; ks < 2; ++ks) {
          const int cld = (ks * 4 + quad) ^ (l15 & 7);
          vf[nd][ks] =
              *(const short8*)(&Vs[buf][(nd * 16 + l15) * 64 + cld * 8]);
        }

      // ---- per i-frag: exp -> P -> LDS -> PV  (2KB per-wave scratch)
#pragma unroll
      for (int f = 0; f < 2; ++f) {
        const bool need_mask = (j0 + 63 > q0w + f * 16);
        const int ig = q0w + f * 16 + l15;
#pragma unroll
        for (int nj = 0; nj < 4; ++nj) {
          float p[4];
#pragma unroll
          for (int r = 0; r < 4; ++r) {
            float e = __builtin_amdgcn_exp2f(st[f][nj][r]);
            if (need_mask) {
              const int jg = j0 + nj * 16 + quad * 4 + r;
              e = (jg > ig) ? 0.f : e;
            }
            lpart[f] += e;
            p[r] = e;
          }
          // rows j = nj*16+quad*4 .. +3 are consecutive -> one b64 write
          const int c = nj * 2 + (quad >> 1);
          const int cld = c ^ (l15 & 7);
          uint2v pk;
          pk[0] = f2bf_u(p[0]) | (f2bf_u(p[1]) << 16);
          pk[1] = f2bf_u(p[2]) | (f2bf_u(p[3]) << 16);
          *(uint2v*)(&pw[l15 * 64 + cld * 8 + (quad & 1) * 4]) = pk;
        }
        // wave-local: drain P writes (lanes lockstep; DS ops in-order)
        __asm__ volatile("s_waitcnt lgkmcnt(0)" ::: "memory");

        short8 pf[2];
#pragma unroll
        for (int ks = 0; ks < 2; ++ks) {
          const int cld = (ks * 4 + quad) ^ (l15 & 7);
          pf[ks] = *(const short8*)(&pw[l15 * 64 + cld * 8]);
        }
#pragma unroll
        for (int nd = 0; nd < 4; ++nd)
#pragma unroll
          for (int ks = 0; ks < 2; ++ks)
            o[f][nd] = mfma16(vf[nd][ks], pf[ks], o[f][nd]);
        __asm__ volatile("" ::: "memory");  // keep f=1 P writes after pf reads
      }
    }
    __syncthreads();
  }

  // ---- final row sums: i = l15 -> only 2 cross-quad shuffles per frag
  float inv[2];
#pragma unroll
  for (int f = 0; f < 2; ++f) {
    float s2 = lpart[f];
    s2 += __shfl_xor(s2, 16);
    s2 += __shfl_xor(s2, 32);
    inv[f] = 1.0f / s2;
  }

  // ---- un-transpose O via per-wave LDS (16x64 per pass), coalesced stores
#pragma unroll
  for (int f = 0; f < 2; ++f) {
#pragma unroll
    for (int nd = 0; nd < 4; ++nd) {
      const int c = nd * 2 + (quad >> 1);
      const int cld = c ^ (l15 & 7);
      uint2v pk;
      pk[0] =
          f2bf_u(o[f][nd][0] * inv[f]) | (f2bf_u(o[f][nd][1] * inv[f]) << 16);
      pk[1] =
          f2bf_u(o[f][nd][2] * inv[f]) | (f2bf_u(o[f][nd][3] * inv[f]) << 16);
      *(uint2v*)(&pw[l15 * 64 + cld * 8 + (quad & 1) * 4]) = pk;
    }
    __asm__ volatile("s_waitcnt lgkmcnt(0)" ::: "memory");
#pragma unroll
    for (int ps = 0; ps < 2; ++ps) {
      const int r16 = ps * 8 + (lane >> 3);  // 0..15
      const int cn = lane & 7;
      const int cldr = cn ^ (r16 & 7);
      const short8 val = *(const short8*)(&pw[r16 * 64 + cldr * 8]);
      *(short8*)(att + (size_t)(b * Tn + q0w + f * 16 + r16) * Cn + h * 64 +
                 cn * 8) = val;
    }
    __asm__ volatile("" ::: "memory");  // f=1 writes stay after f=0 reads
  }
#undef STAGE
}

// ---------------------------------------------------------------- launch
extern "C" void kernel_launch(void* const* d_in, const int* in_sizes, int n_in,
                              void* d_out, int out_size, void* d_ws,
                              size_t ws_size, hipStream_t stream) {
  const float* x = (const float*)d_in[0];      // [B,T,C]
  const float* w_qkv = (const float*)d_in[1];  // [3C,C]
  const float* w_out = (const float*)d_in[2];  // [C,C]
  const float* b_out = (const float*)d_in[3];  // [C]
  float* out = (float*)d_out;                  // [B,T,C] fp32

  // Workspace layout (75.5 MB total):
  short* xb = (short*)d_ws;                      // 8192*1024  x bf16
  short* wqb = xb + (size_t)8192 * 1024;         // 3072*1024  w_qkv bf16
  short* wob = wqb + (size_t)3072 * 1024;        // 1024*1024  w_out bf16
  short* qkb = wob + (size_t)1024 * 1024;        // 8192*2048  q|k bf16 (q pre-scaled)
  short* vtb = qkb + (size_t)8192 * 2048;        // 64*64*2048 v transposed
  short* att = xb;  // x is dead after GEMM1; reuse for attention output

  // One fused cast: dst segments (xb|wqb|wob) are contiguous in ws.
  cast3_kernel<<<dim3((G_X + G_WQ + G_WO) / 256), 256, 0, stream>>>(
      x, w_qkv, w_out, xb);

  // QKV projection: M=8192, N=3072, K=1024 -- 256^2 8-phase kernel,
  // grid dim3(8,48): blockIdx.x == XCD id (linear%8), by -> (m fast, n slow)
  gemm_qkv<<<dim3(8, 48), 512, 0, stream>>>(xb, wqb, qkb, vtb);
  // Flash attention: bh = x (XCD-affine), qt descending globally
  attn_kernel<<<dim3(64, 16), 256, 0, stream>>>(qkb, vtb, att);
  // Output projection: M=8192, N=1024, K=1024, +bias, fp32 out
  gemm_bt<1><<<dim3(64, 8), 256, 0, stream>>>(att, wob, 8192, 1024, 1024,
                                              nullptr, nullptr, b_out, out);
}

// Round 5
// 240.752 us; speedup vs baseline: 1.0585x; 1.0097x over previous
//
#include <hip/hip_runtime.h>

// Problem constants (B,T,C,H fixed by the reference).
constexpr int Bn = 4, Tn = 2048, Cn = 1024, Hn = 16, Dn = 64;

typedef __attribute__((ext_vector_type(8))) short short8;
typedef __attribute__((ext_vector_type(4))) float floatx4;
typedef __attribute__((ext_vector_type(2))) unsigned uint2v;

#define DEVFN __device__ __forceinline__

// exp(s/8) = exp2(s * log2e/8); folded into Q at GEMM1 epilogue.
constexpr float SCL = 0.18033688011112042f;

// RTNE float -> bf16 raw bits (inputs are finite; no NaN handling needed).
DEVFN unsigned f2bf_u(float f) {
  unsigned u = __builtin_bit_cast(unsigned, f);
  u += 0x7fffu + ((u >> 16) & 1u);
  return u >> 16;
}
DEVFN short f2bf(float f) { return (short)f2bf_u(f); }

DEVFN floatx4 mfma16(short8 a, short8 b, floatx4 c) {
  return __builtin_amdgcn_mfma_f32_16x16x32_bf16(a, b, c, 0, 0, 0);
}

// Async global->LDS, 16B/lane. LDS dest must be wave-uniform base + lane*16.
DEVFN void gld_lds16(const void* g, void* l) {
  __builtin_amdgcn_global_load_lds(
      (const __attribute__((address_space(1))) unsigned*)g,
      (__attribute__((address_space(3))) unsigned*)l, 16, 0, 0);
}

// ---------------------------------------------------------------- fused fp32->bf16
// One kernel casts all three inputs; destinations are contiguous in ws
// (xb | wqb | wob), so dst indexes by the global group id directly.
constexpr int G_X = 8192 * 1024 / 8;   // 1048576 groups of 8
constexpr int G_WQ = 3072 * 1024 / 8;  // 393216
constexpr int G_WO = 1024 * 1024 / 8;  // 131072
__global__ __launch_bounds__(256) void cast3_kernel(
    const float* __restrict__ x, const float* __restrict__ wq,
    const float* __restrict__ wo, short* __restrict__ dst) {
  const int i = blockIdx.x * 256 + threadIdx.x;
  const float* src;
  int rel;
  if (i < G_X) {
    src = x; rel = i;
  } else if (i < G_X + G_WQ) {
    src = wq; rel = i - G_X;
  } else {
    src = wo; rel = i - (G_X + G_WQ);
  }
  const floatx4* p = (const floatx4*)src + (size_t)rel * 2;
  floatx4 a = p[0], b = p[1];
  short8 r;
  r[0] = f2bf(a[0]); r[1] = f2bf(a[1]); r[2] = f2bf(a[2]); r[3] = f2bf(a[3]);
  r[4] = f2bf(b[0]); r[5] = f2bf(b[1]); r[6] = f2bf(b[2]); r[7] = f2bf(b[3]);
  ((short8*)dst)[i] = r;
}

// ---------------------------------------------------------------- GEMM  Y = A @ B^T
// 2-phase 128x128 tile, BK=64, XOR-swizzled LDS (16B chunk ^= row&7) applied
// on the stager's GLOBAL address (fragment b128 reads conflict-free while the
// LDS side keeps gld_lds16's required uniform+lane*16 mapping).
// R1-R4 post-mortem: an 8-phase 256^2 counted-vmcnt port (m201 template) was
// tried for MODE 0 and LOST (83-107us vs 76us here): 128KB LDS -> 1 block/CU
// -> zero TLP, and at K=1024 (16 K-tiles) + 1.5 grid rounds the lockstep
// barrier chain stalls on every L2 miss (MfmaUtil 19-23%, HBM <1.9TB/s).
// This 2-phase kernel keeps ~5 blocks/CU of TLP and is the proven local
// optimum at this shape (m97-structure tile-space: 128^2 > 128x256 > 256^2).
// MODE 0: QKV projection. Q cols [0,1024) PRE-SCALED by log2e/8 (softmax
//         fold). Q|K -> qkb [M,2048]; V cols [2048,3072) written transposed
//         into vtb[B][H][D][T] (b64-packed: consecutive acc regs = consecutive t).
// MODE 1: output projection: fp32 out + bias.
template <int MODE>
__global__ __launch_bounds__(256, 2) void gemm_bt(
    const short* __restrict__ A, const short* __restrict__ Bw, int M, int N, int K,
    short* __restrict__ qkb, short* __restrict__ vtb,
    const float* __restrict__ bias, float* __restrict__ fout) {
  __shared__ short As[128 * 64];  // 16 KB, [row][chunk^(row&7)] of 8-short chunks
  __shared__ short Bs[128 * 64];
  const int tid = threadIdx.x;
  const int lane = tid & 63, wave = tid >> 6;
  const int l15 = lane & 15, quad = lane >> 4;
  const int wr = wave >> 1, wc = wave & 1;
  const int m0 = blockIdx.x * 128, n0 = blockIdx.y * 128;

  // Staging slot: thread = (row r0 = tid>>3, chunk cs = tid&7); it-pass adds
  // +32 rows (swizzle invariant: (r+32)&7 == r&7). Global chunk = cs^(r&7).
  const int r0 = tid >> 3, cs = tid & 7;
  const short* Ag = A + (size_t)(m0 + r0) * K + (cs ^ (r0 & 7)) * 8;
  const short* Bg = Bw + (size_t)(n0 + r0) * K + (cs ^ (r0 & 7)) * 8;

  floatx4 acc[4][4] = {};

  for (int k0 = 0; k0 < K; k0 += 64) {
#pragma unroll
    for (int it = 0; it < 4; ++it) {
      gld_lds16(Ag + k0 + (size_t)(it * 32) * K, As + it * 2048 + tid * 8);
      gld_lds16(Bg + k0 + (size_t)(it * 32) * K, Bs + it * 2048 + tid * 8);
    }
    __syncthreads();
#pragma unroll
    for (int ks = 0; ks < 2; ++ks) {
      short8 af[4], bf[4];
#pragma unroll
      for (int i = 0; i < 4; ++i) {
        const int row = wr * 64 + i * 16 + l15;
        af[i] = *(const short8*)(As + row * 64 +
                                 ((ks * 4 + quad) ^ (l15 & 7)) * 8);
      }
#pragma unroll
      for (int i = 0; i < 4; ++i) {
        const int row = wc * 64 + i * 16 + l15;
        bf[i] = *(const short8*)(Bs + row * 64 +
                                 ((ks * 4 + quad) ^ (l15 & 7)) * 8);
      }
#pragma unroll
      for (int mi = 0; mi < 4; ++mi)
#pragma unroll
        for (int ni = 0; ni < 4; ++ni)
          acc[mi][ni] = mfma16(af[mi], bf[ni], acc[mi][ni]);
    }
    __syncthreads();
  }

  // Epilogue. C/D layout: col = lane&15 (n), row = quad*4 + reg (m). [m89/m91]
#pragma unroll
  for (int mi = 0; mi < 4; ++mi) {
    const int row0 = m0 + wr * 64 + mi * 16 + quad * 4;
#pragma unroll
    for (int ni = 0; ni < 4; ++ni) {
      const int col = n0 + wc * 64 + ni * 16 + l15;
      if constexpr (MODE == 0) {
        if (col < 2 * Cn) {  // wave-uniform branch (128 | 2048 alignment)
#pragma unroll
          for (int r = 0; r < 4; ++r) {
            float v = acc[mi][ni][r];
            if (col < Cn) v *= SCL;  // softmax scale folded into Q
            qkb[(size_t)(row0 + r) * (2 * Cn) + col] = f2bf(v);
          }
        } else {
          const int hc = col - 2 * Cn;
          const int hh = hc >> 6, d = hc & 63;
          const int bb = row0 >> 11, t = row0 & (Tn - 1);
          uint2v pk;
          pk[0] = f2bf_u(acc[mi][ni][0]) | (f2bf_u(acc[mi][ni][1]) << 16);
          pk[1] = f2bf_u(acc[mi][ni][2]) | (f2bf_u(acc[mi][ni][3]) << 16);
          *(uint2v*)(vtb + ((size_t)((bb * Hn + hh) * Dn + d)) * Tn + t) = pk;
        }
      } else {
#pragma unroll
        for (int r = 0; r < 4; ++r)
          fout[(size_t)(row0 + r) * N + col] = acc[mi][ni][r] + bias[col];
      }
    }
  }
}

// ---------------------------------------------------------------- flash attention
// Block = 4 waves; wave owns 32 Q rows (2 i-frags). KV tile = 64, double-
// buffered LDS via async global_load_lds, ONE barrier per tile. XOR-swizzled
// LDS layouts (16B chunk ^= row&7) applied on the stager's GLOBAL address.
// Transposed math: S^T = K.Q^T, O^T = V^T.P^T; no online max; per-lane row
// sums reduced once at the end. P round-trip through per-wave 2KB LDS is done
// PER i-frag (LDS 40KB -> 4 blocks/CU).
//
// Grid dim3(64,16): bh = x; qt from a balance LUT on g = blockIdx.y.
// 1024 blocks fill exactly the 1024 resident slots (4/CU) -> NO dynamic
// rebalancing; with plain descending qt a CU's four blocks (one per dispatch
// quartile under round-robin assignment) sum to 56..80 tiles (+-18%). The
// nibble LUT 0x32104567ba98cdef makes every quartile column (g,g+4,g+8,g+12)
// sum to qt-total 30 -> uniform 68 tiles/CU. Heaviest tiles (qt=15,14,13,12)
// still dispatch first; linear id % 8 = bh % 8 keeps one bh per XCD (L2
// keeps its K/V). Performance heuristic only -- correctness never depends on
// placement.
// T5 setprio(1) wraps both MFMA clusters: 4 independent blocks/CU at
// different phases is the regime where it measured +4-7% (m191); null only
// for lockstep grids (m190).
// launch_bounds(256,3): VGPR cap 170 -- (256,4) forced 64 VGPRs and spilled
// ~217 MB of scratch to HBM (R4 WRITE_SIZE smoking gun). Don't tighten it.
__global__ __launch_bounds__(256, 3) void attn_kernel(
    const short* __restrict__ qk, const short* __restrict__ vt,
    short* __restrict__ att) {
  __shared__ short Ks[2][64 * 64];
  __shared__ short Vs[2][64 * 64];
  __shared__ short Ps[4][16 * 64];  // per-wave P-frag scratch (2 KB)

  const int bh = blockIdx.x;  // 0..63
  // Balance LUT: g -> qt, columns (g, g+4, g+8, g+12) each sum to 30.
  const int qt =
      (int)((0x32104567ba98cdefULL >> (blockIdx.y * 4)) & 0xFULL);
  const int b = bh >> 4, h = bh & 15;
  const int tid = threadIdx.x;
  const int lane = tid & 63, wave = tid >> 6;
  const int l15 = lane & 15, quad = lane >> 4;
  const int q0w = qt * 128 + wave * 32;  // this wave's 32 Q rows

  const short* qbase = qk + (size_t)(b * Tn) * 2048 + h * 64;
  const short* kbase = qbase + 1024;
  const short* vbase = vt + (size_t)(bh * 64) * Tn;
  short* pw = Ps[wave];

  // Q^T fragments (B-operand rows [i][c]) in registers for the whole kernel.
  short8 qf[2][2];
#pragma unroll
  for (int f = 0; f < 2; ++f)
#pragma unroll
    for (int ks = 0; ks < 2; ++ks)
      qf[f][ks] = *(const short8*)(qbase + (size_t)(q0w + f * 16 + l15) * 2048 +
                                   ks * 32 + quad * 8);

  floatx4 o[2][4] = {};         // O^T accumulator [f][nd], C-layout (row=d, col=i)
  float lpart[2] = {0.f, 0.f};  // per-lane row sums (i = l15)

  const int wave_nt = ((q0w + 31) >> 6) + 1;  // tiles this wave computes
  const int block_nt = 2 * qt + 2;            // loop count (uniform per block)

  const int jr = tid >> 3;  // staging row 0..31 (+32 on 2nd pass)
  const int cl = tid & 7;   // staging LDS chunk

#define STAGE(JT, BUF)                                                       \
  {                                                                          \
    const int j0s = (JT) * 64;                                               \
    _Pragma("unroll") for (int it = 0; it < 2; ++it) {                       \
      const int row = jr + it * 32;                                          \
      const int cg = cl ^ (row & 7);                                         \
      gld_lds16(kbase + (size_t)(j0s + row) * 2048 + cg * 8,                 \
                &Ks[BUF][it * 2048 + tid * 8]);                              \
      gld_lds16(vbase + (size_t)row * Tn + j0s + cg * 8,                     \
                &Vs[BUF][it * 2048 + tid * 8]);                              \
    }                                                                        \
  }

  STAGE(0, 0)
  __syncthreads();

  for (int jt = 0; jt < block_nt; ++jt) {
    const int buf = jt & 1;
    if (jt + 1 < block_nt) STAGE(jt + 1, buf ^ 1)

    if (jt < wave_nt) {
      const int j0 = jt * 64;

      // ---- S^T = K.Q^T for both i-frags; kf in 2 batches (VGPR economy)
      floatx4 st[2][4];
#pragma unroll
      for (int f = 0; f < 2; ++f)
#pragma unroll
        for (int nj = 0; nj < 4; ++nj) st[f][nj] = floatx4{0.f, 0.f, 0.f, 0.f};
#pragma unroll
      for (int half = 0; half < 2; ++half) {
        short8 kfa[2][2];
#pragma unroll
        for (int j2 = 0; j2 < 2; ++j2)
#pragma unroll
          for (int ks = 0; ks < 2; ++ks) {
            const int cld = (ks * 4 + quad) ^ (l15 & 7);
            kfa[j2][ks] = *(const short8*)(
                &Ks[buf][((half * 2 + j2) * 16 + l15) * 64 + cld * 8]);
          }
        __builtin_amdgcn_s_setprio(1);
#pragma unroll
        for (int f = 0; f < 2; ++f)
#pragma unroll
          for (int j2 = 0; j2 < 2; ++j2)
#pragma unroll
            for (int ks = 0; ks < 2; ++ks)
              st[f][half * 2 + j2] =
                  mfma16(kfa[j2][ks], qf[f][ks], st[f][half * 2 + j2]);
        __builtin_amdgcn_s_setprio(0);
      }

      // ---- V^T fragments (A-operand rows [d][j]), shared by both i-frags
      short8 vf[4][2];
#pragma unroll
      for (int nd = 0; nd < 4; ++nd)
#pragma unroll
        for (int ks = 0; ks < 2; ++ks) {
          const int cld = (ks * 4 + quad) ^ (l15 & 7);
          vf[nd][ks] =
              *(const short8*)(&Vs[buf][(nd * 16 + l15) * 64 + cld * 8]);
        }

      // ---- per i-frag: exp -> P -> LDS -> PV  (2KB per-wave scratch)
#pragma unroll
      for (int f = 0; f < 2; ++f) {
        const bool need_mask = (j0 + 63 > q0w + f * 16);
        const int ig = q0w + f * 16 + l15;
#pragma unroll
        for (int nj = 0; nj < 4; ++nj) {
          float p[4];
#pragma unroll
          for (int r = 0; r < 4; ++r) {
            float e = __builtin_amdgcn_exp2f(st[f][nj][r]);
            if (need_mask) {
              const int jg = j0 + nj * 16 + quad * 4 + r;
              e = (jg > ig) ? 0.f : e;
            }
            lpart[f] += e;
            p[r] = e;
          }
          // rows j = nj*16+quad*4 .. +3 are consecutive -> one b64 write
          const int c = nj * 2 + (quad >> 1);
          const int cld = c ^ (l15 & 7);
          uint2v pk;
          pk[0] = f2bf_u(p[0]) | (f2bf_u(p[1]) << 16);
          pk[1] = f2bf_u(p[2]) | (f2bf_u(p[3]) << 16);
          *(uint2v*)(&pw[l15 * 64 + cld * 8 + (quad & 1) * 4]) = pk;
        }
        // wave-local: drain P writes (lanes lockstep; DS ops in-order)
        __asm__ volatile("s_waitcnt lgkmcnt(0)" ::: "memory");

        short8 pf[2];
#pragma unroll
        for (int ks = 0; ks < 2; ++ks) {
          const int cld = (ks * 4 + quad) ^ (l15 & 7);
          pf[ks] = *(const short8*)(&pw[l15 * 64 + cld * 8]);
        }
        __builtin_amdgcn_s_setprio(1);
#pragma unroll
        for (int nd = 0; nd < 4; ++nd)
#pragma unroll
          for (int ks = 0; ks < 2; ++ks)
            o[f][nd] = mfma16(vf[nd][ks], pf[ks], o[f][nd]);
        __builtin_amdgcn_s_setprio(0);
        __asm__ volatile("" ::: "memory");  // keep f=1 P writes after pf reads
      }
    }
    __syncthreads();
  }

  // ---- final row sums: i = l15 -> only 2 cross-quad shuffles per frag
  float inv[2];
#pragma unroll
  for (int f = 0; f < 2; ++f) {
    float s2 = lpart[f];
    s2 += __shfl_xor(s2, 16);
    s2 += __shfl_xor(s2, 32);
    inv[f] = 1.0f / s2;
  }

  // ---- un-transpose O via per-wave LDS (16x64 per pass), coalesced stores
#pragma unroll
  for (int f = 0; f < 2; ++f) {
#pragma unroll
    for (int nd = 0; nd < 4; ++nd) {
      const int c = nd * 2 + (quad >> 1);
      const int cld = c ^ (l15 & 7);
      uint2v pk;
      pk[0] =
          f2bf_u(o[f][nd][0] * inv[f]) | (f2bf_u(o[f][nd][1] * inv[f]) << 16);
      pk[1] =
          f2bf_u(o[f][nd][2] * inv[f]) | (f2bf_u(o[f][nd][3] * inv[f]) << 16);
      *(uint2v*)(&pw[l15 * 64 + cld * 8 + (quad & 1) * 4]) = pk;
    }
    __asm__ volatile("s_waitcnt lgkmcnt(0)" ::: "memory");
#pragma unroll
    for (int ps = 0; ps < 2; ++ps) {
      const int r16 = ps * 8 + (lane >> 3);  // 0..15
      const int cn = lane & 7;
      const int cldr = cn ^ (r16 & 7);
      const short8 val = *(const short8*)(&pw[r16 * 64 + cldr * 8]);
      *(short8*)(att + (size_t)(b * Tn + q0w + f * 16 + r16) * Cn + h * 64 +
                 cn * 8) = val;
    }
    __asm__ volatile("" ::: "memory");  // f=1 writes stay after f=0 reads
  }
#undef STAGE
}

// ---------------------------------------------------------------- launch
extern "C" void kernel_launch(void* const* d_in, const int* in_sizes, int n_in,
                              void* d_out, int out_size, void* d_ws,
                              size_t ws_size, hipStream_t stream) {
  const float* x = (const float*)d_in[0];      // [B,T,C]
  const float* w_qkv = (const float*)d_in[1];  // [3C,C]
  const float* w_out = (const float*)d_in[2];  // [C,C]
  const float* b_out = (const float*)d_in[3];  // [C]
  float* out = (float*)d_out;                  // [B,T,C] fp32

  // Workspace layout (75.5 MB total):
  short* xb = (short*)d_ws;                      // 8192*1024  x bf16
  short* wqb = xb + (size_t)8192 * 1024;         // 3072*1024  w_qkv bf16
  short* wob = wqb + (size_t)3072 * 1024;        // 1024*1024  w_out bf16
  short* qkb = wob + (size_t)1024 * 1024;        // 8192*2048  q|k bf16 (q pre-scaled)
  short* vtb = qkb + (size_t)8192 * 2048;        // 64*64*2048 v transposed
  short* att = xb;  // x is dead after GEMM1; reuse for attention output

  // One fused cast: dst segments (xb|wqb|wob) are contiguous in ws.
  cast3_kernel<<<dim3((G_X + G_WQ + G_WO) / 256), 256, 0, stream>>>(
      x, w_qkv, w_out, xb);

  // QKV projection: M=8192, N=3072, K=1024 (proven 2-phase kernel)
  gemm_bt<0><<<dim3(64, 24), 256, 0, stream>>>(xb, wqb, 8192, 3072, 1024, qkb,
                                               vtb, nullptr, nullptr);
  // Flash attention: bh = x (XCD-affine), qt via per-CU balance LUT
  attn_kernel<<<dim3(64, 16), 256, 0, stream>>>(qkb, vtb, att);
  // Output projection: M=8192, N=1024, K=1024, +bias, fp32 out
  gemm_bt<1><<<dim3(64, 8), 256, 0, stream>>>(att, wob, 8192, 1024, 1024,
                                              nullptr, nullptr, b_out, out);
}

// Round 6
// 227.024 us; speedup vs baseline: 1.1225x; 1.0605x over previous
//
#include <hip/hip_runtime.h>

// Problem constants (B,T,C,H fixed by the reference).
constexpr int Bn = 4, Tn = 2048, Cn = 1024, Hn = 16, Dn = 64;

typedef __attribute__((ext_vector_type(8))) short short8;
typedef __attribute__((ext_vector_type(4))) float floatx4;
typedef __attribute__((ext_vector_type(2))) unsigned uint2v;
typedef __attribute__((ext_vector_type(4))) unsigned uint4v;

#define DEVFN __device__ __forceinline__

// exp(s/8) = exp2(s * log2e/8); folded into Q at GEMM1 epilogue.
constexpr float SCL = 0.18033688011112042f;

// RTNE float -> bf16 raw bits (inputs are finite; no NaN handling needed).
DEVFN unsigned f2bf_u(float f) {
  unsigned u = __builtin_bit_cast(unsigned, f);
  u += 0x7fffu + ((u >> 16) & 1u);
  return u >> 16;
}
DEVFN short f2bf(float f) { return (short)f2bf_u(f); }

// Packed RTNE f32x2 -> bf16x2 in one VALU op (no builtin on gfx950 -- T12
// primitive). Replaces ~12 integer ops per pair; R5 showed attn VALU-bound
// (VALUBusy 53% vs MfmaUtil 19%) with manual f2bf packing ~45% of the VALU.
DEVFN unsigned cvtpk(float lo, float hi) {
  unsigned r;
  asm("v_cvt_pk_bf16_f32 %0, %1, %2" : "=v"(r) : "v"(lo), "v"(hi));
  return r;
}

DEVFN floatx4 mfma16(short8 a, short8 b, floatx4 c) {
  return __builtin_amdgcn_mfma_f32_16x16x32_bf16(a, b, c, 0, 0, 0);
}

// Async global->LDS, 16B/lane. LDS dest must be wave-uniform base + lane*16.
DEVFN void gld_lds16(const void* g, void* l) {
  __builtin_amdgcn_global_load_lds(
      (const __attribute__((address_space(1))) unsigned*)g,
      (__attribute__((address_space(3))) unsigned*)l, 16, 0, 0);
}

// ---------------------------------------------------------------- fused fp32->bf16
// One kernel casts all three inputs; destinations are contiguous in ws
// (xb | wqb | wob), so dst indexes by the global group id directly.
constexpr int G_X = 8192 * 1024 / 8;   // 1048576 groups of 8
constexpr int G_WQ = 3072 * 1024 / 8;  // 393216
constexpr int G_WO = 1024 * 1024 / 8;  // 131072
__global__ __launch_bounds__(256) void cast3_kernel(
    const float* __restrict__ x, const float* __restrict__ wq,
    const float* __restrict__ wo, short* __restrict__ dst) {
  const int i = blockIdx.x * 256 + threadIdx.x;
  const float* src;
  int rel;
  if (i < G_X) {
    src = x; rel = i;
  } else if (i < G_X + G_WQ) {
    src = wq; rel = i - G_X;
  } else {
    src = wo; rel = i - (G_X + G_WQ);
  }
  const floatx4* p = (const floatx4*)src + (size_t)rel * 2;
  floatx4 a = p[0], b = p[1];
  uint4v r;
  r[0] = cvtpk(a[0], a[1]);
  r[1] = cvtpk(a[2], a[3]);
  r[2] = cvtpk(b[0], b[1]);
  r[3] = cvtpk(b[2], b[3]);
  ((uint4v*)dst)[i] = r;
}

// ---------------------------------------------------------------- GEMM  Y = A @ B^T
// 2-phase 128x128 tile, BK=64, XOR-swizzled LDS (16B chunk ^= row&7) applied
// on the stager's GLOBAL address (fragment b128 reads conflict-free while the
// LDS side keeps gld_lds16's required uniform+lane*16 mapping).
// R1-R4 post-mortem: an 8-phase 256^2 counted-vmcnt port (m201 template) was
// tried for MODE 0 and LOST (83-107us vs 76us here): 128KB LDS -> 1 block/CU
// -> zero TLP, and at K=1024 (16 K-tiles) + 1.5 grid rounds the lockstep
// barrier chain stalls on every L2 miss (MfmaUtil 19-23%, HBM <1.9TB/s).
// This 2-phase kernel keeps ~5 blocks/CU of TLP and is the proven local
// optimum at this shape (m97-structure tile-space: 128^2 > 128x256 > 256^2).
// MODE 0: QKV projection. Q cols [0,1024) PRE-SCALED by log2e/8 (softmax
//         fold). Q|K -> qkb [M,2048]; V cols [2048,3072) written transposed
//         into vtb[B][H][D][T] (b64-packed: consecutive acc regs = consecutive t).
// MODE 1: output projection: fp32 out + bias.
template <int MODE>
__global__ __launch_bounds__(256, 2) void gemm_bt(
    const short* __restrict__ A, const short* __restrict__ Bw, int M, int N, int K,
    short* __restrict__ qkb, short* __restrict__ vtb,
    const float* __restrict__ bias, float* __restrict__ fout) {
  __shared__ short As[128 * 64];  // 16 KB, [row][chunk^(row&7)] of 8-short chunks
  __shared__ short Bs[128 * 64];
  const int tid = threadIdx.x;
  const int lane = tid & 63, wave = tid >> 6;
  const int l15 = lane & 15, quad = lane >> 4;
  const int wr = wave >> 1, wc = wave & 1;
  const int m0 = blockIdx.x * 128, n0 = blockIdx.y * 128;

  // Staging slot: thread = (row r0 = tid>>3, chunk cs = tid&7); it-pass adds
  // +32 rows (swizzle invariant: (r+32)&7 == r&7). Global chunk = cs^(r&7).
  const int r0 = tid >> 3, cs = tid & 7;
  const short* Ag = A + (size_t)(m0 + r0) * K + (cs ^ (r0 & 7)) * 8;
  const short* Bg = Bw + (size_t)(n0 + r0) * K + (cs ^ (r0 & 7)) * 8;

  floatx4 acc[4][4] = {};

  for (int k0 = 0; k0 < K; k0 += 64) {
#pragma unroll
    for (int it = 0; it < 4; ++it) {
      gld_lds16(Ag + k0 + (size_t)(it * 32) * K, As + it * 2048 + tid * 8);
      gld_lds16(Bg + k0 + (size_t)(it * 32) * K, Bs + it * 2048 + tid * 8);
    }
    __syncthreads();
#pragma unroll
    for (int ks = 0; ks < 2; ++ks) {
      short8 af[4], bf[4];
#pragma unroll
      for (int i = 0; i < 4; ++i) {
        const int row = wr * 64 + i * 16 + l15;
        af[i] = *(const short8*)(As + row * 64 +
                                 ((ks * 4 + quad) ^ (l15 & 7)) * 8);
      }
#pragma unroll
      for (int i = 0; i < 4; ++i) {
        const int row = wc * 64 + i * 16 + l15;
        bf[i] = *(const short8*)(Bs + row * 64 +
                                 ((ks * 4 + quad) ^ (l15 & 7)) * 8);
      }
#pragma unroll
      for (int mi = 0; mi < 4; ++mi)
#pragma unroll
        for (int ni = 0; ni < 4; ++ni)
          acc[mi][ni] = mfma16(af[mi], bf[ni], acc[mi][ni]);
    }
    __syncthreads();
  }

  // Epilogue. C/D layout: col = lane&15 (n), row = quad*4 + reg (m). [m89/m91]
#pragma unroll
  for (int mi = 0; mi < 4; ++mi) {
    const int row0 = m0 + wr * 64 + mi * 16 + quad * 4;
#pragma unroll
    for (int ni = 0; ni < 4; ++ni) {
      const int col = n0 + wc * 64 + ni * 16 + l15;
      if constexpr (MODE == 0) {
        if (col < 2 * Cn) {  // wave-uniform branch (128 | 2048 alignment)
#pragma unroll
          for (int r = 0; r < 4; ++r) {
            float v = acc[mi][ni][r];
            if (col < Cn) v *= SCL;  // softmax scale folded into Q
            qkb[(size_t)(row0 + r) * (2 * Cn) + col] = f2bf(v);
          }
        } else {
          const int hc = col - 2 * Cn;
          const int hh = hc >> 6, d = hc & 63;
          const int bb = row0 >> 11, t = row0 & (Tn - 1);
          uint2v pk;
          pk[0] = cvtpk(acc[mi][ni][0], acc[mi][ni][1]);
          pk[1] = cvtpk(acc[mi][ni][2], acc[mi][ni][3]);
          *(uint2v*)(vtb + ((size_t)((bb * Hn + hh) * Dn + d)) * Tn + t) = pk;
        }
      } else {
#pragma unroll
        for (int r = 0; r < 4; ++r)
          fout[(size_t)(row0 + r) * N + col] = acc[mi][ni][r] + bias[col];
      }
    }
  }
}

// ---------------------------------------------------------------- flash attention
// Block = 4 waves; wave owns 32 Q rows (2 i-frags). KV tile = 64, double-
// buffered LDS via async global_load_lds, ONE barrier per tile. XOR-swizzled
// LDS layouts (16B chunk ^= row&7) applied on the stager's GLOBAL address.
// Transposed math: S^T = K.Q^T, O^T = V^T.P^T; no online max. P round-trip
// through per-wave 2KB LDS is done PER i-frag (LDS 40KB -> 4 blocks/CU).
//
// R5 counters: VALUBusy 53% / MfmaUtil 19% -> VALU-issue-bound. Two cuts:
//  (a) v_cvt_pk_bf16_f32 for all f32->bf16 packing (was ~45% of VALU);
//  (b) row sums via ones-MFMA: A=all-ones bf16 -> D[m][i] = sum_j P[i][j]
//      (2 extra MFMAs/frag/tile on the 80%-idle MFMA pipe) replacing 32
//      v_add_f32/tile-wave AND the final cross-quad shuffles. Denominator
//      now sums bf16-rounded P (matches the bf16 PV numerator; <=0.5% rel).
//
// Grid dim3(64,16): bh = x; qt from a balance LUT on g = blockIdx.y.
// 1024 blocks fill exactly the 1024 resident slots (4/CU) -> NO dynamic
// rebalancing; nibble LUT 0x32104567ba98cdef makes every dispatch-quartile
// column (g,g+4,g+8,g+12) sum to 30 -> uniform 68 tiles/CU. Heaviest first;
// linear id % 8 = bh % 8 keeps one bh per XCD. Heuristic only.
// T5 setprio(1) wraps MFMA clusters (independent blocks/CU regime, m191).
// launch_bounds(256,3): VGPR cap 170 -- (256,4) forced 64 VGPRs and spilled
// ~217 MB of scratch to HBM (R4 WRITE_SIZE smoking gun). Don't tighten it.
__global__ __launch_bounds__(256, 3) void attn_kernel(
    const short* __restrict__ qk, const short* __restrict__ vt,
    short* __restrict__ att) {
  __shared__ short Ks[2][64 * 64];
  __shared__ short Vs[2][64 * 64];
  __shared__ short Ps[4][16 * 64];  // per-wave P-frag scratch (2 KB)

  const int bh = blockIdx.x;  // 0..63
  // Balance LUT: g -> qt, columns (g, g+4, g+8, g+12) each sum to 30.
  const int qt =
      (int)((0x32104567ba98cdefULL >> (blockIdx.y * 4)) & 0xFULL);
  const int b = bh >> 4, h = bh & 15;
  const int tid = threadIdx.x;
  const int lane = tid & 63, wave = tid >> 6;
  const int l15 = lane & 15, quad = lane >> 4;
  const int q0w = qt * 128 + wave * 32;  // this wave's 32 Q rows

  const short* qbase = qk + (size_t)(b * Tn) * 2048 + h * 64;
  const short* kbase = qbase + 1024;
  const short* vbase = vt + (size_t)(bh * 64) * Tn;
  short* pw = Ps[wave];

  // Q^T fragments (B-operand rows [i][c]) in registers for the whole kernel.
  short8 qf[2][2];
#pragma unroll
  for (int f = 0; f < 2; ++f)
#pragma unroll
    for (int ks = 0; ks < 2; ++ks)
      qf[f][ks] = *(const short8*)(qbase + (size_t)(q0w + f * 16 + l15) * 2048 +
                                   ks * 32 + quad * 8);

  // All-ones bf16 A-operand for MFMA row sums (1.0 = 0x3F80).
  short8 ones;
#pragma unroll
  for (int i = 0; i < 8; ++i) ones[i] = (short)0x3F80;

  floatx4 o[2][4] = {};      // O^T accumulator [f][nd], C-layout (row=d, col=i)
  floatx4 sum_acc[2] = {};   // MFMA row-sum acc: D[m][i] identical over m

  const int wave_nt = ((q0w + 31) >> 6) + 1;  // tiles this wave computes
  const int block_nt = 2 * qt + 2;            // loop count (uniform per block)

  const int jr = tid >> 3;  // staging row 0..31 (+32 on 2nd pass)
  const int cl = tid & 7;   // staging LDS chunk

#define STAGE(JT, BUF)                                                       \
  {                                                                          \
    const int j0s = (JT) * 64;                                               \
    _Pragma("unroll") for (int it = 0; it < 2; ++it) {                       \
      const int row = jr + it * 32;                                          \
      const int cg = cl ^ (row & 7);                                         \
      gld_lds16(kbase + (size_t)(j0s + row) * 2048 + cg * 8,                 \
                &Ks[BUF][it * 2048 + tid * 8]);                              \
      gld_lds16(vbase + (size_t)row * Tn + j0s + cg * 8,                     \
                &Vs[BUF][it * 2048 + tid * 8]);                              \
    }                                                                        \
  }

  STAGE(0, 0)
  __syncthreads();

  for (int jt = 0; jt < block_nt; ++jt) {
    const int buf = jt & 1;
    if (jt + 1 < block_nt) STAGE(jt + 1, buf ^ 1)

    if (jt < wave_nt) {
      const int j0 = jt * 64;

      // ---- S^T = K.Q^T for both i-frags; kf in 2 batches (VGPR economy)
      floatx4 st[2][4];
#pragma unroll
      for (int f = 0; f < 2; ++f)
#pragma unroll
        for (int nj = 0; nj < 4; ++nj) st[f][nj] = floatx4{0.f, 0.f, 0.f, 0.f};
#pragma unroll
      for (int half = 0; half < 2; ++half) {
        short8 kfa[2][2];
#pragma unroll
        for (int j2 = 0; j2 < 2; ++j2)
#pragma unroll
          for (int ks = 0; ks < 2; ++ks) {
            const int cld = (ks * 4 + quad) ^ (l15 & 7);
            kfa[j2][ks] = *(const short8*)(
                &Ks[buf][((half * 2 + j2) * 16 + l15) * 64 + cld * 8]);
          }
        __builtin_amdgcn_s_setprio(1);
#pragma unroll
        for (int f = 0; f < 2; ++f)
#pragma unroll
          for (int j2 = 0; j2 < 2; ++j2)
#pragma unroll
            for (int ks = 0; ks < 2; ++ks)
              st[f][half * 2 + j2] =
                  mfma16(kfa[j2][ks], qf[f][ks], st[f][half * 2 + j2]);
        __builtin_amdgcn_s_setprio(0);
      }

      // ---- V^T fragments (A-operand rows [d][j]), shared by both i-frags
      short8 vf[4][2];
#pragma unroll
      for (int nd = 0; nd < 4; ++nd)
#pragma unroll
        for (int ks = 0; ks < 2; ++ks) {
          const int cld = (ks * 4 + quad) ^ (l15 & 7);
          vf[nd][ks] =
              *(const short8*)(&Vs[buf][(nd * 16 + l15) * 64 + cld * 8]);
        }

      // ---- per i-frag: exp -> P(bf16 via cvt_pk) -> LDS -> PV + ones-sum
#pragma unroll
      for (int f = 0; f < 2; ++f) {
        const bool need_mask = (j0 + 63 > q0w + f * 16);
        const int ig = q0w + f * 16 + l15;
#pragma unroll
        for (int nj = 0; nj < 4; ++nj) {
          float p[4];
#pragma unroll
          for (int r = 0; r < 4; ++r) {
            float e = __builtin_amdgcn_exp2f(st[f][nj][r]);
            if (need_mask) {
              const int jg = j0 + nj * 16 + quad * 4 + r;
              e = (jg > ig) ? 0.f : e;
            }
            p[r] = e;
          }
          // rows j = nj*16+quad*4 .. +3 are consecutive -> one b64 write
          const int c = nj * 2 + (quad >> 1);
          const int cld = c ^ (l15 & 7);
          uint2v pk;
          pk[0] = cvtpk(p[0], p[1]);
          pk[1] = cvtpk(p[2], p[3]);
          *(uint2v*)(&pw[l15 * 64 + cld * 8 + (quad & 1) * 4]) = pk;
        }
        // wave-local: drain P writes (lanes lockstep; DS ops in-order)
        __asm__ volatile("s_waitcnt lgkmcnt(0)" ::: "memory");

        short8 pf[2];
#pragma unroll
        for (int ks = 0; ks < 2; ++ks) {
          const int cld = (ks * 4 + quad) ^ (l15 & 7);
          pf[ks] = *(const short8*)(&pw[l15 * 64 + cld * 8]);
        }
        __builtin_amdgcn_s_setprio(1);
#pragma unroll
        for (int nd = 0; nd < 4; ++nd)
#pragma unroll
          for (int ks = 0; ks < 2; ++ks)
            o[f][nd] = mfma16(vf[nd][ks], pf[ks], o[f][nd]);
#pragma unroll
        for (int ks = 0; ks < 2; ++ks)
          sum_acc[f] = mfma16(ones, pf[ks], sum_acc[f]);
        __builtin_amdgcn_s_setprio(0);
        __asm__ volatile("" ::: "memory");  // keep f=1 P writes after pf reads
      }
    }
    __syncthreads();
  }

  // ---- row sums came out of the ones-MFMA: every reg of sum_acc[f] holds
  // sum_j P[i][j] for this lane's i = l15 (identical across m) -> no shuffles.
  float inv[2];
#pragma unroll
  for (int f = 0; f < 2; ++f) inv[f] = 1.0f / sum_acc[f][0];

  // ---- un-transpose O via per-wave LDS (16x64 per pass), coalesced stores
#pragma unroll
  for (int f = 0; f < 2; ++f) {
#pragma unroll
    for (int nd = 0; nd < 4; ++nd) {
      const int c = nd * 2 + (quad >> 1);
      const int cld = c ^ (l15 & 7);
      uint2v pk;
      pk[0] = cvtpk(o[f][nd][0] * inv[f], o[f][nd][1] * inv[f]);
      pk[1] = cvtpk(o[f][nd][2] * inv[f], o[f][nd][3] * inv[f]);
      *(uint2v*)(&pw[l15 * 64 + cld * 8 + (quad & 1) * 4]) = pk;
    }
    __asm__ volatile("s_waitcnt lgkmcnt(0)" ::: "memory");
#pragma unroll
    for (int ps = 0; ps < 2; ++ps) {
      const int r16 = ps * 8 + (lane >> 3);  // 0..15
      const int cn = lane & 7;
      const int cldr = cn ^ (r16 & 7);
      const short8 val = *(const short8*)(&pw[r16 * 64 + cldr * 8]);
      *(short8*)(att + (size_t)(b * Tn + q0w + f * 16 + r16) * Cn + h * 64 +
                 cn * 8) = val;
    }
    __asm__ volatile("" ::: "memory");  // f=1 writes stay after f=0 reads
  }
#undef STAGE
}

// ---------------------------------------------------------------- launch
extern "C" void kernel_launch(void* const* d_in, const int* in_sizes, int n_in,
                              void* d_out, int out_size, void* d_ws,
                              size_t ws_size, hipStream_t stream) {
  const float* x = (const float*)d_in[0];      // [B,T,C]
  const float* w_qkv = (const float*)d_in[1];  // [3C,C]
  const float* w_out = (const float*)d_in[2];  // [C,C]
  const float* b_out = (const float*)d_in[3];  // [C]
  float* out = (float*)d_out;                  // [B,T,C] fp32

  // Workspace layout (75.5 MB total):
  short* xb = (short*)d_ws;                      // 8192*1024  x bf16
  short* wqb = xb + (size_t)8192 * 1024;         // 3072*1024  w_qkv bf16
  short* wob = wqb + (size_t)3072 * 1024;        // 1024*1024  w_out bf16
  short* qkb = wob + (size_t)1024 * 1024;        // 8192*2048  q|k bf16 (q pre-scaled)
  short* vtb = qkb + (size_t)8192 * 2048;        // 64*64*2048 v transposed
  short* att = xb;  // x is dead after GEMM1; reuse for attention output

  // One fused cast: dst segments (xb|wqb|wob) are contiguous in ws.
  cast3_kernel<<<dim3((G_X + G_WQ + G_WO) / 256), 256, 0, stream>>>(
      x, w_qkv, w_out, xb);

  // QKV projection: M=8192, N=3072, K=1024 (proven 2-phase kernel)
  gemm_bt<0><<<dim3(64, 24), 256, 0, stream>>>(xb, wqb, 8192, 3072, 1024, qkb,
                                               vtb, nullptr, nullptr);
  // Flash attention: bh = x (XCD-affine), qt via per-CU balance LUT
  attn_kernel<<<dim3(64, 16), 256, 0, stream>>>(qkb, vtb, att);
  // Output projection: M=8192, N=1024, K=1024, +bias, fp32 out
  gemm_bt<1><<<dim3(64, 8), 256, 0, stream>>>(att, wob, 8192, 1024, 1024,
                                              nullptr, nullptr, b_out, out);
}